// Round 4
// baseline (634.387 us; speedup 1.0000x reference)
//
#include <hip/hip_runtime.h>
#include <cstdint>

// TriplaneEncoding, fp32 I/O. N=2^20 points, 4 levels (r=128,256,512,1024),
// C=4, 3 planes.  out[n, l*12 + p*4 + c] = plane_bilinear * line
// Line sample is degenerate: line = w(t) * 0.5*(TL[p,c,r/2-1] + TL[p,c,r/2]).
//
// R8 design: R0-R3 establish t = bytes / ~3.85 TB/s with 64B fetch granules;
// random point order makes every sample a fresh line (720 MB fetch). Fix the
// ORDER: Morton counting-sort (64^3 buckets) + chunked XCD swizzle so nearby
// points (which share quad lines at L0/L1/L2) are processed adjacently on the
// same XCD L2.  Outputs written at original n (192B = 3 full lines, no RMW).
// Tiers: sorted (286MB ws) > R3 plain-quad (268MB, verified) > direct.

typedef float f32x4 __attribute__((ext_vector_type(4)));

// ---------------- quad-table workspace layout (float4-slot units) ----------------
static constexpr int Q1_0 = 0;
static constexpr int Q1_1 = 199692;             // + 4*3*129^2
static constexpr int Q1_2 = 992280;             // + 4*3*257^2
static constexpr int Q1_3 = 4150308;            // + 4*3*513^2
static constexpr int Q1_END = 16757808;         // + 4*3*1025^2
static constexpr int S1_OFF = Q1_END * 4;       // float offset 67031232 (48 floats)
static constexpr size_t WS1_NEED = ((size_t)S1_OFF + 48) * sizeof(float); // ~268.1 MB

// ---------------- sort scratch (float-word offsets, after S) ----------------
static constexpr int NBUCK  = 262144;           // 64^3 morton buckets
static constexpr int HIST_F = S1_OFF + 64;      // 262144 u32
static constexpr int BSUM_F = HIST_F + NBUCK;   // 1024 u32
static constexpr int XS_F   = BSUM_F + 1024;    // N float4 (16B-aligned)

// ==================== prep: pre-gathered 2x2 quads, all levels + S ====================
__global__ __launch_bounds__(256) void prep_quads_all(
        const float* __restrict__ tp0, const float* __restrict__ tp1,
        const float* __restrict__ tp2, const float* __restrict__ tp3,
        const float* __restrict__ tl0, const float* __restrict__ tl1,
        const float* __restrict__ tl2, const float* __restrict__ tl3,
        float* __restrict__ ws) {
    int t = blockIdx.x * 256 + threadIdx.x;
    if (t < 48) {   // line constants: rows r/2-1, r/2 at weight 0.5 each
        int ll = t / 12, rem = t % 12, pp = rem >> 2, cc = rem & 3;
        const float* tl = (ll == 0) ? tl0 : (ll == 1) ? tl1 : (ll == 2) ? tl2 : tl3;
        int r = 128 << ll;
        const float* row = tl + (size_t)((pp << 2) + cc) * r;
        int y0 = (r >> 1) - 1;
        ws[S1_OFF + t] = 0.5f * row[y0] + 0.5f * row[y0 + 1];
    }
    if (t >= Q1_END) return;
    const float* src; int lvl, base;
    if (t < Q1_1)      { src = tp0; lvl = 0; base = Q1_0; }
    else if (t < Q1_2) { src = tp1; lvl = 1; base = Q1_1; }
    else if (t < Q1_3) { src = tp2; lvl = 2; base = Q1_2; }
    else               { src = tp3; lvl = 3; base = Q1_3; }
    int lt = t - base;
    int q = lt >> 2, s = lt & 3;                // quad id, corner slot
    int r = 128 << lvl, R = r + 1, rr_shift = 2 * (7 + lvl);
    int RR = R * R;
    int p   = q / RR;
    int rem = q - p * RR;
    int yq  = rem / R;
    int xq  = rem - yq * R;
    int tx = xq - 1 + (s & 1);
    int ty = yq - 1 + (s >> 1);
    float4 o = {0.f, 0.f, 0.f, 0.f};
    if ((unsigned)tx < (unsigned)r && (unsigned)ty < (unsigned)r) {
        const float* sp = src + ((size_t)(p << 2) << rr_shift) + (size_t)ty * r + tx;
        o.x = sp[0];
        o.y = sp[(size_t)1 << rr_shift];
        o.z = sp[(size_t)2 << rr_shift];
        o.w = sp[(size_t)3 << rr_shift];
    }
    reinterpret_cast<float4*>(ws)[t] = o;       // identity-indexed by slot
}

// ---------------- helpers ----------------
struct BilinW {
    int i00, i10, i01, i11;
    float w00, w10, w01, w11;
};

__device__ __forceinline__ BilinW bilin_weights(int r, float u, float v) {
    float fr = (float)r;
    float fx = (u + 1.0f) * 0.5f * fr - 0.5f;
    float fy = (v + 1.0f) * 0.5f * fr - 0.5f;
    float x0f = floorf(fx), y0f = floorf(fy);
    float wx = fx - x0f, wy = fy - y0f;
    int x0 = (int)x0f, y0 = (int)y0f;
    int x1 = x0 + 1, y1 = y0 + 1;
    float vx0 = ((unsigned)x0 < (unsigned)r) ? 1.0f : 0.0f;
    float vx1 = ((unsigned)x1 < (unsigned)r) ? 1.0f : 0.0f;
    float vy0 = ((unsigned)y0 < (unsigned)r) ? 1.0f : 0.0f;
    float vy1 = ((unsigned)y1 < (unsigned)r) ? 1.0f : 0.0f;
    int x0c = min(max(x0, 0), r - 1), x1c = min(max(x1, 0), r - 1);
    int y0c = min(max(y0, 0), r - 1), y1c = min(max(y1, 0), r - 1);
    BilinW b;
    b.i00 = y0c * r + x0c; b.i10 = y0c * r + x1c;
    b.i01 = y1c * r + x0c; b.i11 = y1c * r + x1c;
    b.w00 = (1.0f - wx) * (1.0f - wy) * vx0 * vy0;
    b.w10 = wx * (1.0f - wy) * vx1 * vy0;
    b.w01 = (1.0f - wx) * wy * vx0 * vy1;
    b.w11 = wx * wy * vx1 * vy1;
    return b;
}

__device__ __forceinline__ float line_w(float t) {
    float fx = (t + 1.0f) * 0.5f - 0.5f;     // W = 1 axis
    float x0f = floorf(fx);
    float wx = fx - x0f;
    int x0 = (int)x0f;
    float w = 0.0f;
    if (x0 == 0) w += 1.0f - wx;
    if (x0 == -1) w += wx;
    return w;
}

// ---------------- morton sort machinery ----------------
__device__ __forceinline__ unsigned spread3(unsigned v) {   // 6->18 bit spread
    v &= 63u;
    v = (v | (v << 8)) & 0x00F00Fu;
    v = (v | (v << 4)) & 0x0C30C3u;
    v = (v | (v << 2)) & 0x249249u;
    return v;
}

__device__ __forceinline__ unsigned mkey(float x, float y, float z) {
    int qx = min(63, max(0, (int)(x * 64.0f)));
    int qy = min(63, max(0, (int)(y * 64.0f)));
    int qz = min(63, max(0, (int)(z * 64.0f)));
    return spread3(qx) | (spread3(qy) << 1) | (spread3(qz) << 2);
}

__global__ __launch_bounds__(256) void hist_pts(const float* __restrict__ x,
                                                unsigned* __restrict__ hist, int N) {
    int n = blockIdx.x * 256 + threadIdx.x;
    if (n >= N) return;
    unsigned k = mkey(x[n * 3 + 0], x[n * 3 + 1], x[n * 3 + 2]);
    atomicAdd(&hist[k], 1u);
}

__global__ __launch_bounds__(256) void reduce_hist(const unsigned* __restrict__ hist,
                                                   unsigned* __restrict__ bsum) {
    __shared__ unsigned lds[256];
    int t = threadIdx.x;
    lds[t] = hist[blockIdx.x * 256 + t];
    __syncthreads();
    for (int off = 128; off > 0; off >>= 1) {
        if (t < off) lds[t] += lds[t + off];
        __syncthreads();
    }
    if (t == 0) bsum[blockIdx.x] = lds[0];
}

__global__ __launch_bounds__(1024) void scan_bsum(unsigned* __restrict__ bsum) {
    __shared__ unsigned tmp[1024];
    int t = threadIdx.x;
    unsigned v = bsum[t];
    tmp[t] = v;
    __syncthreads();
    for (int off = 1; off < 1024; off <<= 1) {
        unsigned add = (t >= off) ? tmp[t - off] : 0u;
        __syncthreads();
        tmp[t] += add;
        __syncthreads();
    }
    bsum[t] = tmp[t] - v;       // exclusive
}

__global__ __launch_bounds__(256) void scan_hist(unsigned* __restrict__ hist,
                                                 const unsigned* __restrict__ bsum) {
    __shared__ unsigned tmp[256];
    int t = threadIdx.x;
    int base = blockIdx.x * 256;
    unsigned v = hist[base + t];
    tmp[t] = v;
    __syncthreads();
    for (int off = 1; off < 256; off <<= 1) {
        unsigned add = (t >= off) ? tmp[t - off] : 0u;
        __syncthreads();
        tmp[t] += add;
        __syncthreads();
    }
    hist[base + t] = tmp[t] - v + bsum[blockIdx.x];     // global exclusive offset
}

__global__ __launch_bounds__(256) void scatter_pts(const float* __restrict__ x,
                                                   unsigned* __restrict__ offs,
                                                   float4* __restrict__ xs, int N) {
    int n = blockIdx.x * 256 + threadIdx.x;
    if (n >= N) return;
    float xv = x[n * 3 + 0], yv = x[n * 3 + 1], zv = x[n * 3 + 2];
    unsigned k = mkey(xv, yv, zv);
    unsigned pos = atomicAdd(&offs[k], 1u);
    float4 v;
    v.x = xv * 2.0f - 1.0f;
    v.y = yv * 2.0f - 1.0f;
    v.z = zv * 2.0f - 1.0f;
    v.w = __int_as_float(n);
    xs[pos] = v;
}

// ==================== main (sorted): thread = (sorted point, level*3+plane) ====================
template <bool VEC4OUT>
__global__ __launch_bounds__(256) void tri12s(const float4* __restrict__ xs,
                                              const f32x4* __restrict__ ws4,
                                              const float* __restrict__ S,
                                              float* __restrict__ out, int N) {
    int bid = blockIdx.x;
    int nb = gridDim.x;
    if ((nb & 7) == 0) {                 // chunked XCD swizzle (bijective)
        int cpx = nb >> 3;
        bid = (bid & 7) * cpx + (bid >> 3);
    }
    int gid = bid * 256 + threadIdx.x;
    int m = gid / 12;
    int k = gid - m * 12;        // k = l*3 + p
    if (m >= N) return;
    float4 xv = xs[m];
    float ax = xv.x, ay = xv.y, az = xv.z;
    int n = __float_as_int(xv.w);
    int l = k / 3;
    int p = k - l * 3;
    // plane p (u = W axis, v = H axis): p0:(x,z) p1:(y,x) p2:(z,y)
    float u = (p == 0) ? ax : (p == 1) ? ay : az;
    float v = (p == 0) ? az : (p == 1) ? ax : ay;
    float lw = line_w(u);
    f32x4 s = reinterpret_cast<const f32x4*>(S)[k];

    int r = 128 << l, R = r + 1;
    float fr = (float)r;
    float fx = (u + 1.0f) * 0.5f * fr - 0.5f;
    float fy = (v + 1.0f) * 0.5f * fr - 0.5f;
    float x0f = floorf(fx), y0f = floorf(fy);
    float wx = fx - x0f, wy = fy - y0f;
    int ix = (int)x0f + 1;
    int iy = (int)y0f + 1;
    ix = min(max(ix, 0), R - 1);
    iy = min(max(iy, 0), R - 1);
    int qbase = (l == 0) ? Q1_0 : (l == 1) ? Q1_1 : (l == 2) ? Q1_2 : Q1_3;
    const f32x4* Q = ws4 + qbase + (size_t)((p * R + iy) * R + ix) * 4;
    f32x4 q0 = Q[0], q1 = Q[1], q2 = Q[2], q3 = Q[3];
    float w00 = (1.0f - wx) * (1.0f - wy), w10 = wx * (1.0f - wy);
    float w01 = (1.0f - wx) * wy,          w11 = wx * wy;
    f32x4 o = q0 * w00 + q1 * w10 + q2 * w01 + q3 * w11;
    o = o * (s * lw);

    size_t oslot = (size_t)n * 12 + k;
    if (VEC4OUT) {
        __builtin_nontemporal_store(o, reinterpret_cast<f32x4*>(out) + oslot);
    } else {
        size_t base = oslot * 4;
        out[base + 0] = o.x; out[base + 1] = o.y;
        out[base + 2] = o.z; out[base + 3] = o.w;
    }
}

// ==================== main (plain, R3-verified) ====================
template <bool VEC4OUT>
__global__ __launch_bounds__(256) void tri12q(const float* __restrict__ x,
                                              const f32x4* __restrict__ ws4,
                                              const float* __restrict__ S,
                                              float* __restrict__ out, int N) {
    int gid = blockIdx.x * 256 + threadIdx.x;
    int n = gid / 12;
    int k = gid - n * 12;
    if (n >= N) return;
    float ax = x[n * 3 + 0] * 2.0f - 1.0f;
    float ay = x[n * 3 + 1] * 2.0f - 1.0f;
    float az = x[n * 3 + 2] * 2.0f - 1.0f;
    int l = k / 3;
    int p = k - l * 3;
    float u = (p == 0) ? ax : (p == 1) ? ay : az;
    float v = (p == 0) ? az : (p == 1) ? ax : ay;
    float lw = line_w(u);
    f32x4 s = reinterpret_cast<const f32x4*>(S)[k];

    int r = 128 << l, R = r + 1;
    float fr = (float)r;
    float fx = (u + 1.0f) * 0.5f * fr - 0.5f;
    float fy = (v + 1.0f) * 0.5f * fr - 0.5f;
    float x0f = floorf(fx), y0f = floorf(fy);
    float wx = fx - x0f, wy = fy - y0f;
    int ix = (int)x0f + 1;
    int iy = (int)y0f + 1;
    ix = min(max(ix, 0), R - 1);
    iy = min(max(iy, 0), R - 1);
    int qbase = (l == 0) ? Q1_0 : (l == 1) ? Q1_1 : (l == 2) ? Q1_2 : Q1_3;
    const f32x4* Q = ws4 + qbase + (size_t)((p * R + iy) * R + ix) * 4;
    f32x4 q0 = Q[0], q1 = Q[1], q2 = Q[2], q3 = Q[3];
    float w00 = (1.0f - wx) * (1.0f - wy), w10 = wx * (1.0f - wy);
    float w01 = (1.0f - wx) * wy,          w11 = wx * wy;
    f32x4 o = q0 * w00 + q1 * w10 + q2 * w01 + q3 * w11;
    o = o * (s * lw);

    if (VEC4OUT) {
        __builtin_nontemporal_store(o, reinterpret_cast<f32x4*>(out) + gid);
    } else {
        size_t base = (size_t)gid * 4;
        out[base + 0] = o.x; out[base + 1] = o.y;
        out[base + 2] = o.z; out[base + 3] = o.w;
    }
}

// ==================== fallback: direct layout ====================
__global__ __launch_bounds__(256) void tri_direct(
        const float* __restrict__ x,
        const float* __restrict__ tp0, const float* __restrict__ tp1,
        const float* __restrict__ tp2, const float* __restrict__ tp3,
        const float* __restrict__ tl0, const float* __restrict__ tl1,
        const float* __restrict__ tl2, const float* __restrict__ tl3,
        float* __restrict__ out, int N) {
    int n = blockIdx.x * blockDim.x + threadIdx.x;
    if (n >= N) return;
    float ax = x[n * 3 + 0] * 2.0f - 1.0f;
    float ay = x[n * 3 + 1] * 2.0f - 1.0f;
    float az = x[n * 3 + 2] * 2.0f - 1.0f;
    const float U[3] = {ax, ay, az};
    const float V[3] = {az, ax, ay};
    const float LW[3] = {line_w(ax), line_w(ay), line_w(az)};
    const float* TP[4] = {tp0, tp1, tp2, tp3};
    const float* TL[4] = {tl0, tl1, tl2, tl3};

#pragma unroll
    for (int l = 0; l < 4; ++l) {
        const int r = 128 << l;
        const int rr = r * r;
        const int y0 = (r >> 1) - 1;
#pragma unroll
        for (int p = 0; p < 3; ++p) {
            const float* G = TP[l] + (size_t)(p * 4) * rr;
            BilinW b = bilin_weights(r, U[p], V[p]);
            const float w = LW[p];
#pragma unroll
            for (int c = 0; c < 4; ++c) {
                const float* Gc = G + (size_t)c * rr;
                float acc = Gc[b.i00] * b.w00 + Gc[b.i10] * b.w10 +
                            Gc[b.i01] * b.w01 + Gc[b.i11] * b.w11;
                const float* row = TL[l] + (size_t)((p << 2) + c) * r;
                float s = 0.5f * row[y0] + 0.5f * row[y0 + 1];
                out[(size_t)n * 48 + l * 12 + p * 4 + c] = acc * (s * w);
            }
        }
    }
}

extern "C" void kernel_launch(void* const* d_in, const int* in_sizes, int n_in,
                              void* d_out, int out_size, void* d_ws, size_t ws_size,
                              hipStream_t stream) {
    const float* x = (const float*)d_in[0];
    const float* tp[4];
    const float* tl[4];
    // setup_inputs() dict order is interleaved: x, tp0, tl0, tp1, tl1, ...
    bool interleaved = (n_in >= 9) && (in_sizes[2] == 1536);
    for (int l = 0; l < 4; ++l) {
        if (interleaved) {
            tp[l] = (const float*)d_in[1 + 2 * l];
            tl[l] = (const float*)d_in[2 + 2 * l];
        } else {
            tp[l] = (const float*)d_in[1 + l];
            tl[l] = (const float*)d_in[5 + l];
        }
    }
    int N = in_sizes[0] / 3;
    float* out = (float*)d_out;
    bool out16 = (((uintptr_t)d_out & 15u) == 0);
    bool ws64 = (((uintptr_t)d_ws & 63u) == 0);

    size_t need_sorted = ((size_t)XS_F + 4ull * (size_t)N) * sizeof(float);

    if (ws_size >= need_sorted && ws64) {
        // tier 1: morton-sorted quad path
        float* ws = (float*)d_ws;
        unsigned* hist = reinterpret_cast<unsigned*>(ws + HIST_F);
        unsigned* bsum = reinterpret_cast<unsigned*>(ws + BSUM_F);
        float4*   xs   = reinterpret_cast<float4*>(ws + XS_F);
        int gN = (N + 255) / 256;

        prep_quads_all<<<(Q1_END + 255) / 256, 256, 0, stream>>>(
            tp[0], tp[1], tp[2], tp[3], tl[0], tl[1], tl[2], tl[3], ws);
        hipMemsetAsync(hist, 0, (size_t)NBUCK * sizeof(unsigned), stream);
        hist_pts<<<gN, 256, 0, stream>>>(x, hist, N);
        reduce_hist<<<NBUCK / 256, 256, 0, stream>>>(hist, bsum);
        scan_bsum<<<1, 1024, 0, stream>>>(bsum);
        scan_hist<<<NBUCK / 256, 256, 0, stream>>>(hist, bsum);
        scatter_pts<<<gN, 256, 0, stream>>>(x, hist, xs, N);

        long long total = 12LL * N;
        int grid = (int)((total + 255) / 256);
        if (out16) {
            tri12s<true><<<grid, 256, 0, stream>>>(
                xs, (const f32x4*)ws, ws + S1_OFF, out, N);
        } else {
            tri12s<false><<<grid, 256, 0, stream>>>(
                xs, (const f32x4*)ws, ws + S1_OFF, out, N);
        }
    } else if (ws_size >= WS1_NEED && ws64) {
        // tier 2: R3-verified plain quad path
        float* ws = (float*)d_ws;
        prep_quads_all<<<(Q1_END + 255) / 256, 256, 0, stream>>>(
            tp[0], tp[1], tp[2], tp[3], tl[0], tl[1], tl[2], tl[3], ws);
        long long total = 12LL * N;
        int grid = (int)((total + 255) / 256);
        if (out16) {
            tri12q<true><<<grid, 256, 0, stream>>>(
                x, (const f32x4*)ws, ws + S1_OFF, out, N);
        } else {
            tri12q<false><<<grid, 256, 0, stream>>>(
                x, (const f32x4*)ws, ws + S1_OFF, out, N);
        }
    } else {
        int grid = (N + 255) / 256;
        tri_direct<<<grid, 256, 0, stream>>>(
            x, tp[0], tp[1], tp[2], tp[3], tl[0], tl[1], tl[2], tl[3], out, N);
    }
}